// Round 6
// baseline (386.381 us; speedup 1.0000x reference)
//
#include <hip/hip_runtime.h>
#include <hip/hip_bf16.h>

typedef __attribute__((ext_vector_type(8))) short short8;
typedef __attribute__((ext_vector_type(4))) float f32x4;

#define XT_IMG_BYTES (66*66*256*2)         // 2,230,272 per sample
#define XT_TOTAL_BYTES (32LL*XT_IMG_BYTES) // 71,368,704
#define WM_ROW_BYTES (2304*2)              // 4608
#define WM_IMG_BYTES (256*WM_ROW_BYTES)    // 1,179,648

static __device__ __forceinline__ void async16(void* lds, const void* g) {
  __builtin_amdgcn_global_load_lds((const __attribute__((address_space(1))) void*)g,
                                   (__attribute__((address_space(3))) void*)lds, 16, 0, 0);
}
static __device__ __forceinline__ ushort f2bf(float f) {
  __hip_bfloat16 h = __float2bfloat16(f);
  return *reinterpret_cast<ushort*>(&h);
}

// ------- fused prep: xpose (0..8191) | modw (8192..8447) | border (8448..8703) --
__global__ __launch_bounds__(256) void k_prep(const float* __restrict__ x,
                                              const float* __restrict__ W,
                                              const float* __restrict__ y,
                                              ushort* __restrict__ xT,
                                              ushort* __restrict__ wmod) {
  __shared__ float smem[64][68];
  const int bid = blockIdx.x;
  const int t   = threadIdx.x;

  if (bid < 8192) {
    // ---- x [b][c][h][w] fp32 -> xT [b][h+1][w+1][c] bf16 (interior)
    const int b  = bid >> 8;
    const int h  = (bid >> 2) & 63;
    const int c0 = (bid & 3) << 6;
    const float* xp = x + (size_t)(b * 256 + c0) * 4096 + h * 64;
#pragma unroll
    for (int j = 0; j < 4; ++j) {
      const int lin = j * 1024 + t * 4;
      const int il = lin >> 6, c = lin & 63;
      *(float4*)&smem[il][c] = *(const float4*)(xp + (size_t)il * 4096 + c);
    }
    __syncthreads();
    const int q  = t & 7;    // channel octet
    const int w0 = t >> 3;   // 0..31
    ushort* op = xT + (size_t)b * (66 * 66 * 256) + ((size_t)(h + 1) * 66 + 1) * 256 + c0;
#pragma unroll
    for (int j = 0; j < 2; ++j) {
      const int wl = j * 32 + w0;
      short8 v;
#pragma unroll
      for (int k2 = 0; k2 < 8; ++k2) v[k2] = (short)f2bf(smem[8 * q + k2][wl]);
      *(short8*)(op + (size_t)wl * 256 + 8 * q) = v;  // 16B stores
    }
  } else if (bid < 8448) {
    // ---- modulate+demodulate weights: one block per o, loop over b
    float* red = &smem[0][0];
    const int o = bid - 8192;
    const float* wp = W + (size_t)(o * 256 + t) * 9;
    float wr[9];
#pragma unroll
    for (int r = 0; r < 9; ++r) wr[r] = wp[r];
    float ss = 0.f;
#pragma unroll
    for (int r = 0; r < 9; ++r) ss += wr[r] * wr[r];
    const int lane = t & 63, wid = t >> 6;
#pragma unroll 1
    for (int b = 0; b < 32; ++b) {
      const float ym = y[b * 256 + t] + 1.0f;
      float v = ss * ym * ym;
#pragma unroll
      for (int k = 1; k < 64; k <<= 1) v += __shfl_xor(v, k, 64);
      if (lane == 0) red[wid] = v;
      __syncthreads();
      const float tot = red[0] + red[1] + red[2] + red[3];
      const float sc = rsqrtf(tot + 1e-8f) * ym;
      ushort* op = wmod + ((size_t)(b * 256 + o)) * 2304 + t;
#pragma unroll
      for (int r = 0; r < 9; ++r) op[r * 256] = f2bf(wr[r] * sc);
      __syncthreads();
    }
  } else {
    // ---- zero the pad border of xT
    const int zb = bid - 8448;             // 0..255
    const int b  = zb >> 3;
    const int tt = ((zb & 7) << 8) | t;    // 0..2047
    uint4* xT4 = (uint4*)xT;
    const uint4 z = make_uint4(0u, 0u, 0u, 0u);
    uint4* base = xT4 + (size_t)b * (66 * 66 * 32);
    uint4* r0  = base;
    uint4* r65 = base + (size_t)65 * 66 * 32;
    for (int i = tt; i < 2112; i += 2048) { r0[i] = z; r65[i] = z; }
    {
      int r = (tt >> 5) + 1, c = tt & 31;
      base[((size_t)r * 66 + 0)  * 32 + c] = z;
      base[((size_t)r * 66 + 65) * 32 + c] = z;
    }
  }
}

// ---------------- implicit-GEMM conv, 256x256 tile, BK=32, 8 waves --------------
// Cross-iteration fragment double-buffer: body j computes 32 MFMAs on fragments
// read in body j-1 while reading tile j+1's fragments and staging tile j+3.
// MFMAs never depend on same-body reads -> LDS pipe and matrix pipe overlap
// (previously serialized: tile time was their SUM).
// 4-slot LDS ring (4 x 32 KiB), ONE barrier/tile, counted vmcnt(4):
//   invariant at body j start: tiles <= j+1 landed, tile j+2 in flight.
//   body j: read tile j+1 (slot (j+1)&3), stage tile j+3 (slot (j+3)&3,
//   overwrites tile j-1 whose reads finished 2 barriers ago), vmcnt(4), barrier.
// BK=32 rows are 64 B, fully swept by each 16-row frag read -> conflict-free
// with LINEAR layout (no swizzle needed anywhere).
__global__ __launch_bounds__(512, 2) void k_gemm(const ushort* __restrict__ wmod,
                                                 const ushort* __restrict__ xT,
                                                 const float* __restrict__ bias,
                                                 float* __restrict__ out) {
  __shared__ ushort lds[4 * 16384];  // slot: A [256][32] @ +0, B [256][32] @ +8192

  const int t  = threadIdx.x;
  const int bx = blockIdx.x;
  const int xcd = bx & 7;                   // hw round-robins blocks over XCDs
  const int idx = bx >> 3;                  // 0..63
  const int b   = xcd + ((idx >> 4) << 3);  // 4 samples per XCD
  const int tn  = idx & 15;                 // N-tile: 4 image rows
  const int n0  = tn << 8;
  const int h0  = tn << 2;

  const int ln = t & 15;          // lane&15 -> fragment row/col
  const int kq = (t >> 4) & 3;    // lane>>4 -> k-granule (8 bf16)
  const int wv = t >> 6;
  const int wm = wv >> 2;         // 0..1  (128 output rows each)
  const int wn = wv & 3;          // 0..3  (64 output cols each)

  const char* wmodB = (const char*)wmod + (size_t)b * WM_IMG_BYTES;
  const char* xTB   = (const char*)xT   + (size_t)b * XT_IMG_BYTES;

  // staging: granule n = t (A rows 0-127) / 512+t (rows 128-255); row=n>>2,g=n&3
  const int rowA = t >> 2;
  const int g16  = (t & 3) << 4;
  const int gAoff0 = rowA * WM_ROW_BYTES + g16;
  const int gAoff1 = (128 + rowA) * WM_ROW_BYTES + g16;
  const int pix0 = rowA, pix1 = 128 + rowA;
  const int gBoff0 = ((h0 + (pix0 >> 6)) * 66 + (pix0 & 63)) * 512 + g16;
  const int gBoff1 = ((h0 + (pix1 >> 6)) * 66 + (pix1 & 63)) * 512 + g16;

  // fragment read bases (ushort units); frag stride = 16 rows = 512 ushorts
  const int aBase = (wm * 128 + ln) * 32 + kq * 8;
  const int bBase = (wn * 64  + ln) * 32 + kq * 8;

  f32x4 acc[8][4];
  const f32x4 z4 = {0.f, 0.f, 0.f, 0.f};
#pragma unroll
  for (int i = 0; i < 8; ++i)
#pragma unroll
    for (int j = 0; j < 4; ++j) acc[i][j] = z4;

  short8 FA0, FA1, FA2, FA3, FA4, FA5, FA6, FA7, FB0, FB1, FB2, FB3;
  short8 NA0, NA1, NA2, NA3, NA4, NA5, NA6, NA7, NB0, NB1, NB2, NB3;

#define MFC(MI, NI, A, B) acc[MI][NI] = __builtin_amdgcn_mfma_f32_16x16x32_bf16(A, B, acc[MI][NI], 0, 0, 0)
#define FENCE() __builtin_amdgcn_sched_barrier(0)
#define BAR()   __builtin_amdgcn_s_barrier()
#define SGB(M, N) __builtin_amdgcn_sched_group_barrier((M), (N), 0)

#define MFMA32(C)                                                                             \
    MFC(0,0,C##A0,C##B0); MFC(1,0,C##A1,C##B0); MFC(2,0,C##A2,C##B0); MFC(3,0,C##A3,C##B0);   \
    MFC(4,0,C##A4,C##B0); MFC(5,0,C##A5,C##B0); MFC(6,0,C##A6,C##B0); MFC(7,0,C##A7,C##B0);   \
    MFC(0,1,C##A0,C##B1); MFC(1,1,C##A1,C##B1); MFC(2,1,C##A2,C##B1); MFC(3,1,C##A3,C##B1);   \
    MFC(4,1,C##A4,C##B1); MFC(5,1,C##A5,C##B1); MFC(6,1,C##A6,C##B1); MFC(7,1,C##A7,C##B1);   \
    MFC(0,2,C##A0,C##B2); MFC(1,2,C##A1,C##B2); MFC(2,2,C##A2,C##B2); MFC(3,2,C##A3,C##B2);   \
    MFC(4,2,C##A4,C##B2); MFC(5,2,C##A5,C##B2); MFC(6,2,C##A6,C##B2); MFC(7,2,C##A7,C##B2);   \
    MFC(0,3,C##A0,C##B3); MFC(1,3,C##A1,C##B3); MFC(2,3,C##A2,C##B3); MFC(3,3,C##A3,C##B3);   \
    MFC(4,3,C##A4,C##B3); MFC(5,3,C##A5,C##B3); MFC(6,3,C##A6,C##B3); MFC(7,3,C##A7,C##B3)

// body J: consume C-frags (tile J), read R-frags (tile J+1), stage tile J+3
#define BODY(J, C, R, SEN, VMN) do {                                          \
    const int j_ = (J);                                                       \
    asm volatile("s_waitcnt lgkmcnt(0)" ::: "memory");                        \
    FENCE();                                                                  \
    const ushort* sA_ = lds + (((j_ + 1) & 3) << 14);                         \
    const ushort* sB_ = sA_ + 8192;                                           \
    R##A0 = *(const short8*)(sA_ + aBase + 0 * 512);                          \
    R##A1 = *(const short8*)(sA_ + aBase + 1 * 512);                          \
    R##A2 = *(const short8*)(sA_ + aBase + 2 * 512);                          \
    R##A3 = *(const short8*)(sA_ + aBase + 3 * 512);                          \
    R##A4 = *(const short8*)(sA_ + aBase + 4 * 512);                          \
    R##A5 = *(const short8*)(sA_ + aBase + 5 * 512);                          \
    R##A6 = *(const short8*)(sA_ + aBase + 6 * 512);                          \
    R##A7 = *(const short8*)(sA_ + aBase + 7 * 512);                          \
    R##B0 = *(const short8*)(sB_ + bBase + 0 * 512);                          \
    R##B1 = *(const short8*)(sB_ + bBase + 1 * 512);                          \
    R##B2 = *(const short8*)(sB_ + bBase + 2 * 512);                          \
    R##B3 = *(const short8*)(sB_ + bBase + 3 * 512);                          \
    if (SEN) {                                                                \
      const int n3_ = j_ + 3;                                                 \
      const int r3_ = n3_ >> 3;                                               \
      const int kh3_ = r3_ / 3, kw3_ = r3_ - kh3_ * 3;                        \
      const int koA3_ = r3_ * 512 + ((n3_ & 7) << 6);                         \
      const int koB3_ = (kh3_ * 66 + kw3_) * 512 + ((n3_ & 7) << 6);          \
      char* dst_ = (char*)lds + ((n3_ & 3) << 15);                            \
      async16(dst_ + t * 16,          wmodB + gAoff0 + koA3_);                \
      async16(dst_ + 8192 + t * 16,   wmodB + gAoff1 + koA3_);                \
      async16(dst_ + 16384 + t * 16,  xTB + gBoff0 + koB3_);                  \
      async16(dst_ + 24576 + t * 16,  xTB + gBoff1 + koB3_);                  \
    }                                                                         \
    __builtin_amdgcn_s_setprio(1);                                            \
    MFMA32(C);                                                                \
    __builtin_amdgcn_s_setprio(0);                                            \
    SGB(0x100, 4); SGB(0x8, 8);                                               \
    SGB(0x100, 4); SGB(0x8, 8);                                               \
    if (SEN) { SGB(0x30, 4); }                                                \
    SGB(0x100, 4); SGB(0x8, 8);                                               \
    SGB(0x8, 8);                                                              \
    asm volatile("s_waitcnt vmcnt(" VMN ")" ::: "memory");                    \
    FENCE(); BAR(); FENCE();                                                  \
  } while (0)

  // ---- prologue: stage tiles 0,1,2 into slots 0,1,2 (all tap r=0)
#pragma unroll
  for (int kt = 0; kt < 3; ++kt) {
    char* dst = (char*)lds + (kt << 15);
    const int ko = kt << 6;
    async16(dst + t * 16,         wmodB + gAoff0 + ko);
    async16(dst + 8192 + t * 16,  wmodB + gAoff1 + ko);
    async16(dst + 16384 + t * 16, xTB + gBoff0 + ko);
    async16(dst + 24576 + t * 16, xTB + gBoff1 + ko);
  }
  asm volatile("s_waitcnt vmcnt(4)" ::: "memory");  // tiles 0,1 landed; 2 in flight
  FENCE(); BAR(); FENCE();

  // ---- pre-read tile 0 fragments into F
  {
    const ushort* sA_ = lds;
    const ushort* sB_ = lds + 8192;
    FA0 = *(const short8*)(sA_ + aBase + 0 * 512);
    FA1 = *(const short8*)(sA_ + aBase + 1 * 512);
    FA2 = *(const short8*)(sA_ + aBase + 2 * 512);
    FA3 = *(const short8*)(sA_ + aBase + 3 * 512);
    FA4 = *(const short8*)(sA_ + aBase + 4 * 512);
    FA5 = *(const short8*)(sA_ + aBase + 5 * 512);
    FA6 = *(const short8*)(sA_ + aBase + 6 * 512);
    FA7 = *(const short8*)(sA_ + aBase + 7 * 512);
    FB0 = *(const short8*)(sB_ + bBase + 0 * 512);
    FB1 = *(const short8*)(sB_ + bBase + 1 * 512);
    FB2 = *(const short8*)(sB_ + bBase + 2 * 512);
    FB3 = *(const short8*)(sB_ + bBase + 3 * 512);
  }

  // ---- main loop: 72 K-tiles of BK=32 (9 taps x 8 channel-blocks)
#pragma unroll 1
  for (int j = 0; j < 68; j += 2) {
    BODY(j,     F, N, 1, "4");
    BODY(j + 1, N, F, 1, "4");
  }
  BODY(68, F, N, 1, "4");
  BODY(69, N, F, 0, "0");
  BODY(70, F, N, 0, "0");
  // ---- final tile 71: consume N, nothing else
  asm volatile("s_waitcnt lgkmcnt(0)" ::: "memory");
  FENCE();
  MFMA32(N);

  // epilogue: C row = o (row=(lane>>4)*4+reg), col = n (lane&15)
  const float* bp = bias + wm * 128;
  float* outB = out + ((size_t)(b * 256 + wm * 128)) * 4096 + n0 + wn * 64 + ln;
#pragma unroll
  for (int mi = 0; mi < 8; ++mi) {
#pragma unroll
    for (int rg = 0; rg < 4; ++rg) {
      const int orow = mi * 16 + kq * 4 + rg;
      const float bv = bp[orow];
      float* po = outB + (size_t)orow * 4096;
#pragma unroll
      for (int ni = 0; ni < 4; ++ni) po[ni * 16] = acc[mi][ni][rg] + bv;
    }
  }
#undef MFC
#undef FENCE
#undef BAR
#undef SGB
#undef MFMA32
#undef BODY
}

extern "C" void kernel_launch(void* const* d_in, const int* in_sizes, int n_in,
                              void* d_out, int out_size, void* d_ws, size_t ws_size,
                              hipStream_t stream) {
  const float* x    = (const float*)d_in[0];   // [32,256,64,64]
  const float* y    = (const float*)d_in[1];   // [32,256]
  const float* W    = (const float*)d_in[2];   // [256,256,3,3]
  const float* bias = (const float*)d_in[3];   // [256]
  float* out = (float*)d_out;                  // [32,256,64,64]

  ushort* xT   = (ushort*)d_ws;                                   // 71,368,704 B
  ushort* wmod = (ushort*)((char*)d_ws + (size_t)XT_TOTAL_BYTES); // 37,748,736 B

  k_prep<<<8704, 256, 0, stream>>>(x, W, y, xT, wmod);
  k_gemm<<<512,  512, 0, stream>>>(wmod, xT, bias, out);
}